// Round 4
// baseline (2873.830 us; speedup 1.0000x reference)
//
#include <hip/hip_runtime.h>
#include <cstdint>

// ---------------------------------------------------------------------------
// SFA pipeline, round 4.
//   - MFMA convs (A bf16, W split hi+lo), pipelined weight prefetch (r3).
//   - grid_sample reads cat (bf16 NHWC) with chunk-major thread map:
//     coalesced 16B corner reads + 512B/pixel coalesced writes.
//   - conv1 emits bf16 NHWC (EPI 1); conv_flow reads it via GLL staging.
//   - heatmap path NHWC (12-float pixel records) for coalesced cost volume.
// ---------------------------------------------------------------------------

constexpr int H = 180, W = 180, HW = H * W;
constexpr int PD = 194, PD2 = PD * PD;          // padded pixel grid

typedef __attribute__((ext_vector_type(8))) short short8;
typedef __attribute__((ext_vector_type(4))) float f32x4;

// ---- workspace layout (bytes) ---------------------------------------------
constexpr size_t OFF_CAT  = 0;                          // ushort B*PD2*320 (96.3MB)
constexpr size_t OFF_F2   = 96348160;                   // ushort B*PD2*256 (77.1MB)
constexpr size_t R2       = OFF_F2 + 77078528;          // 173426688
constexpr size_t OFF_HPN  = R2;                         // float B*HW*12 (6.2MB)
constexpr size_t OFF_HIN  = R2 + 6220800;               // float B*HW*12
constexpr size_t OFF_HBUF = R2;                         // ushort B*PD2*64 (19.3MB, aliases hpn/hin)
constexpr size_t R3       = R2 + 19269632;              // 192696320
constexpr size_t OFF_GO   = R3;                         // ushort B*PD2*128 (38.5MB)
constexpr size_t OFF_FLOW = R3 + 38539264;              // float B*4*HW (2.07MB)
constexpr size_t OFF_WF1  = OFF_FLOW + 2073600;         // 233309184
constexpr size_t OFF_WFG1 = OFF_WF1 + 737280;
constexpr size_t OFF_WFG2 = OFF_WFG1 + 1179648;         // end ~235.8MB

__device__ __forceinline__ unsigned short f2bf(float x) {
    unsigned int u = __builtin_bit_cast(unsigned int, x);
    unsigned int r = (u + 0x7FFFu + ((u >> 16) & 1u)) >> 16;
    return (unsigned short)r;
}
__device__ __forceinline__ float bf2f(unsigned short b) {
    return __builtin_bit_cast(float, (unsigned int)b << 16);
}

#define GLL(SRC, DST) __builtin_amdgcn_global_load_lds(                        \
    (const __attribute__((address_space(1))) unsigned int*)(SRC),              \
    (__attribute__((address_space(3))) unsigned int*)(DST), 16, 0, 0)

// ---------------------------------------------------------------------------
// zero the halo border of a padded NHWC buffer (5236 border px per batch)
__global__ __launch_bounds__(256) void border_zero(unsigned short* __restrict__ buf,
                                                   int CPdiv8, int total) {
    int id = blockIdx.x * 256 + threadIdx.x;
    if (id >= total) return;
    int c8 = id % CPdiv8; int r = id / CPdiv8;
    int pi = r % 5236;    int b = r / 5236;
    int py, px;
    if (pi < 2716) { int ri = pi / 194; py = ri == 0 ? 0 : 180 + ri; px = pi % 194; }
    else { int j = pi - 2716; py = 1 + j / 14; int t = j % 14; px = t == 0 ? 0 : 180 + t; }
    short8 z = {0,0,0,0,0,0,0,0};
    *(short8*)&buf[((size_t)(b * PD + py) * PD + px) * (size_t)(CPdiv8 * 8) + c8 * 8] = z;
}

// ---------------------------------------------------------------------------
// build cat interior: pts -> ch 0..127, img -> ch 128..255 (perm; weights match)
__global__ __launch_bounds__(192) void build_cat(const float* __restrict__ pts,
                                                 const float* __restrict__ img,
                                                 unsigned short* __restrict__ cat) {
    int b = blockIdx.x / 180, h = blockIdx.x % 180;
    int t = threadIdx.x;
    if (t >= 180) return;
    unsigned short* pb = cat + ((size_t)(b * PD + 1 + h) * PD + (1 + t)) * 320;
    const float* ps = pts + (size_t)b * 128 * HW + h * W + t;
    const float* is = img + (size_t)b * 128 * HW + h * W + t;
#pragma unroll 4
    for (int v = 0; v < 16; ++v) {
        short8 o;
#pragma unroll
        for (int e = 0; e < 8; ++e) o[e] = (short)f2bf(ps[(size_t)(v * 8 + e) * HW]);
        *(short8*)&pb[v * 8] = o;
    }
#pragma unroll 4
    for (int v = 0; v < 16; ++v) {
        short8 o;
#pragma unroll
        for (int e = 0; e < 8; ++e) o[e] = (short)f2bf(is[(size_t)(v * 8 + e) * HW]);
        *(short8*)&pb[128 + v * 8] = o;
    }
}

// ---------------------------------------------------------------------------
// heatmap prep: LDS-tiled transpose; out = NHWC 12-float records [b][h][w][12]
__global__ __launch_bounds__(256) void prep_heatmaps(
    const float* __restrict__ hm_pts, const float* __restrict__ hm_img,
    float* __restrict__ hpn, float* __restrict__ hin, int B) {
    __shared__ float s[10][16][17];
    const int t = threadIdx.x;
    const int tsel = blockIdx.z & 1, b = blockIdx.z >> 1;
    const int h0 = blockIdx.y * 16, w0 = blockIdx.x * 16;
    const float* src = tsel ? hm_img : hm_pts;
    float* dst = tsel ? hin : hpn;
    {
        const int th = t & 15, tw = t >> 4;
        const int gh = h0 + th, gw = w0 + tw;
        if (gh < H && gw < W) {
#pragma unroll
            for (int c = 0; c < 10; ++c)
                s[c][tw][th] = src[((size_t)(b * 10 + c) * W + gw) * H + gh];
        }
    }
    __syncthreads();
    const int wq = t & 15, hq = t >> 4;
    const int gh = h0 + hq, gw = w0 + wq;
    if (gh >= H || gw >= W) return;
    float v[10]; float ss = 0.f;
#pragma unroll
    for (int c = 0; c < 10; ++c) {
        float x = s[c][wq][hq];
        float sg = 1.f / (1.f + expf(-x));
        v[c] = sg; ss += sg * sg;
    }
    float inv = 1.f / fmaxf(sqrtf(ss), 1e-12f);
    float* rec = dst + ((size_t)b * HW + gh * W + gw) * 12;
    float4 q0 = {v[0] * inv, v[1] * inv, v[2] * inv, v[3] * inv};
    float4 q1 = {v[4] * inv, v[5] * inv, v[6] * inv, v[7] * inv};
    float4 q2 = {v[8] * inv, v[9] * inv, 0.f, 0.f};
    *(float4*)rec = q0; *(float4*)(rec + 4) = q1; *(float4*)(rec + 8) = q2;
}

// ---------------------------------------------------------------------------
// cost volumes from NHWC records -> cat channels 256..305 (306..319 zero)
__global__ __launch_bounds__(256) void cost_volume_cat(
    const float* __restrict__ hpn, const float* __restrict__ hin,
    unsigned short* __restrict__ cat, int B, int total) {
    int id = blockIdx.x * 256 + threadIdx.x;
    if (id >= total) return;
    int w = id % W; int r = id / W;
    int h = r % H;  int b = r / H;
    const float* hpb = hpn + (size_t)b * HW * 12;
    const float* hib = hin + (size_t)b * HW * 12;
    float hp_l[10], hi_l[10];
    {
        const float* c0 = hpb + (size_t)(h * W + w) * 12;
        const float* c1 = hib + (size_t)(h * W + w) * 12;
        float4 a0 = *(const float4*)c0, a1 = *(const float4*)(c0 + 4);
        float4 a2 = *(const float4*)(c0 + 8);
        float4 b0 = *(const float4*)c1, b1 = *(const float4*)(c1 + 4);
        float4 b2 = *(const float4*)(c1 + 8);
        hp_l[0]=a0.x; hp_l[1]=a0.y; hp_l[2]=a0.z; hp_l[3]=a0.w;
        hp_l[4]=a1.x; hp_l[5]=a1.y; hp_l[6]=a1.z; hp_l[7]=a1.w;
        hp_l[8]=a2.x; hp_l[9]=a2.y;
        hi_l[0]=b0.x; hi_l[1]=b0.y; hi_l[2]=b0.z; hi_l[3]=b0.w;
        hi_l[4]=b1.x; hi_l[5]=b1.y; hi_l[6]=b1.z; hi_l[7]=b1.w;
        hi_l[8]=b2.x; hi_l[9]=b2.y;
    }
    unsigned pk[32];
#pragma unroll
    for (int j = 0; j < 32; ++j) pk[j] = 0;
#pragma unroll
    for (int dy = 0; dy < 5; ++dy)
#pragma unroll
        for (int dx = 0; dx < 5; ++dx) {
            const int k = dy * 5 + dx;
            int yy = h + dy - 2, xx = w + dx - 2;
            float ap = 0.f, ai = 0.f;
            if (yy >= 0 && yy < H && xx >= 0 && xx < W) {
                const float* n0 = hib + (size_t)(yy * W + xx) * 12;
                const float* n1 = hpb + (size_t)(yy * W + xx) * 12;
                float n0v[10], n1v[10];
                {
                    float4 u0=*(const float4*)n0, u1=*(const float4*)(n0+4);
                    float4 u2=*(const float4*)(n0+8);
                    float4 v0=*(const float4*)n1, v1=*(const float4*)(n1+4);
                    float4 v2=*(const float4*)(n1+8);
                    n0v[0]=u0.x;n0v[1]=u0.y;n0v[2]=u0.z;n0v[3]=u0.w;
                    n0v[4]=u1.x;n0v[5]=u1.y;n0v[6]=u1.z;n0v[7]=u1.w;
                    n0v[8]=u2.x;n0v[9]=u2.y;
                    n1v[0]=v0.x;n1v[1]=v0.y;n1v[2]=v0.z;n1v[3]=v0.w;
                    n1v[4]=v1.x;n1v[5]=v1.y;n1v[6]=v1.z;n1v[7]=v1.w;
                    n1v[8]=v2.x;n1v[9]=v2.y;
                }
#pragma unroll
                for (int c = 0; c < 10; ++c) {
                    ap = fmaf(hp_l[c], n0v[c], ap);
                    ai = fmaf(hi_l[c], n1v[c], ai);
                }
            }
            pk[k >> 1] |= (unsigned)f2bf(ap) << ((k & 1) * 16);
            const int kc = 25 + k;
            pk[kc >> 1] |= (unsigned)f2bf(ai) << ((kc & 1) * 16);
        }
    unsigned short* pb = cat + ((size_t)(b * PD + 1 + h) * PD + (1 + w)) * 320 + 256;
#pragma unroll
    for (int v = 0; v < 8; ++v) {
        uint4 q = {pk[v * 4], pk[v * 4 + 1], pk[v * 4 + 2], pk[v * 4 + 3]};
        *(uint4*)((char*)pb + v * 16) = q;
    }
}

// ---------------------------------------------------------------------------
// weight frag transform: w fp32 [oc][Cin][3][3] -> frag-linear bf16 hi/lo.
template <int MODE>
__global__ __launch_bounds__(256) void wfrag_kernel(const float* __restrict__ w,
                                                    unsigned short* __restrict__ wf,
                                                    int Cin, int nOg, int nfrag) {
    int t = blockIdx.x * 256 + threadIdx.x;
    int f = t >> 6, lane = t & 63;
    if (f >= nfrag) return;
    int part = f & 1; int r = f >> 1;
    int og = r % nOg; r /= nOg;
    int tap = r % 9;  int chunk = r / 9;
    int oc = og * 16 + (lane & 15);
    short8 out;
#pragma unroll
    for (int e = 0; e < 8; ++e) {
        int c = chunk * 32 + ((lane >> 4) << 3) + e;
        int rc = c;
        if (MODE == 1) {
            if (c < 128) rc = c;
            else if (c < 256) rc = c + 25;
            else if (c < 281) rc = c - 128;
            else rc = c;
        }
        float val = 0.f;
        if (rc < Cin && (MODE == 0 || c < 306))
            val = w[((size_t)oc * Cin + rc) * 9 + tap];
        unsigned short hi = f2bf(val);
        out[e] = (short)(part == 0 ? hi : f2bf(val - bf2f(hi)));
    }
    *(short8*)&wf[(size_t)f * 512 + lane * 8] = out;
}

// ---------------------------------------------------------------------------
// MFMA conv 3x3 SAME, software-pipelined weights (r3 core, unchanged).
template <int NCH, int COUT, int EPI, bool RELU, int OCB>
__global__ __launch_bounds__(256, 2) void conv_mfma(
    const unsigned short* __restrict__ act,  // padded NHWC, CP = NCH*32
    const unsigned short* __restrict__ wf,
    const float* __restrict__ bias,
    float* __restrict__ outF,                // EPI 0: fp32 NCHW
    unsigned short* __restrict__ outB,       // EPI 1: padded NHWC bf16 (CP=COUT)
    int Bn) {
    constexpr int CP = NCH * 32;
    constexpr int NOG = COUT / 16;
    constexpr int G = OCB / 16;
    __shared__ __align__(16) char ldsAll[2 * 20736 + 8192];

    const int tid = threadIdx.x;
    const int lane = tid & 63, wv = tid >> 6;
    const int zz = blockIdx.z;
    constexpr int NT = COUT / OCB;
    const int bb = zz / NT;
    const int oc0 = (zz % NT) * OCB;
    const int og0 = oc0 >> 4;
    const int y0 = blockIdx.y * 16, x0 = blockIdx.x * 16;

    const char* actB = (const char*)act + (size_t)bb * PD2 * CP * 2;

    unsigned soff[6];
#pragma unroll
    for (int i = 0; i < 6; ++i) {
        int idx = i * 256 + tid;
        int p = idx >> 2, q = idx & 3;
        int yy = p / 18, xx = p % 18;
        soff[i] = ((unsigned)((y0 + yy) * PD + (x0 + xx)) * CP + q * 8) * 2;
    }
    const int alane = (lane & 15) * 32 + ((lane >> 4) << 3);
    const unsigned short* wlane = wf + (size_t)og0 * 1024 + lane * 8;

    f32x4 acc[4][G];
#pragma unroll
    for (int i = 0; i < 4; ++i)
#pragma unroll
        for (int j = 0; j < G; ++j) acc[i][j] = (f32x4){0.f, 0.f, 0.f, 0.f};

    auto stage = [&](int chunk, int bsel) {
        unsigned co = (unsigned)chunk * 64;
#pragma unroll
        for (int i = 0; i < 5; ++i)
            GLL(actB + soff[i] + co,
                ldsAll + (size_t)bsel * 20736 + ((i << 8) + (wv << 6)) * 16);
        if (tid < 16)
            GLL(actB + soff[5] + co,
                ldsAll + (size_t)bsel * 20736 + ((5 << 8)) * 16);
    };
    auto loadW = [&](int idx, short8 (&dh)[G], short8 (&dl)[G]) {
        const unsigned short* p = wlane + (size_t)idx * NOG * 1024;
#pragma unroll
        for (int g = 0; g < G; ++g) {
            dh[g] = *(const short8*)(p + g * 1024);
            dl[g] = *(const short8*)(p + g * 1024 + 512);
        }
    };
    auto compTap = [&](int dy, int dx, const short8 (&bh)[G], const short8 (&bl)[G],
                       const unsigned short* tb) {
        __builtin_amdgcn_s_setprio(1);
#pragma unroll
        for (int rr = 0; rr < 4; ++rr) {
            const int yy = wv * 4 + rr + dy;
            short8 a = *(const short8*)(tb + (yy * 18 + dx) * 32 + alane);
#pragma unroll
            for (int g = 0; g < G; ++g) {
                asm("v_mfma_f32_16x16x32_bf16 %0, %1, %2, %0"
                    : "+v"(acc[rr][g]) : "v"(a), "v"(bh[g]));
                asm("v_mfma_f32_16x16x32_bf16 %0, %1, %2, %0"
                    : "+v"(acc[rr][g]) : "v"(a), "v"(bl[g]));
            }
        }
        __builtin_amdgcn_s_setprio(0);
    };

    short8 wh[2][G], wl[2][G];
    stage(0, 0);
    loadW(0, wh[0], wl[0]);
    asm volatile("s_waitcnt vmcnt(0)" ::: "memory");
    __syncthreads();

    int bsel = 0;
    for (int cp2 = 0; cp2 < NCH / 2; ++cp2) {
#pragma unroll
        for (int par = 0; par < 2; ++par) {
            const int chunk = cp2 * 2 + par;
            const unsigned short* tb = (const unsigned short*)ldsAll + bsel * 10368;
#pragma unroll
            for (int t = 0; t < 9; ++t) {
                const int cb = (t + par) & 1;
                if (t < 8) {
                    if (cb) loadW(chunk * 9 + t + 1, wh[0], wl[0]);
                    else    loadW(chunk * 9 + t + 1, wh[1], wl[1]);
                } else if (chunk + 1 < NCH) {
                    if (cb) loadW((chunk + 1) * 9, wh[0], wl[0]);
                    else    loadW((chunk + 1) * 9, wh[1], wl[1]);
                }
                if (t == 0 && chunk + 1 < NCH) stage(chunk + 1, bsel ^ 1);
                if (cb) compTap(t / 3, t % 3, wh[1], wl[1], tb);
                else    compTap(t / 3, t % 3, wh[0], wl[0], tb);
            }
            asm volatile("s_waitcnt vmcnt(0)" ::: "memory");
            __syncthreads();
            bsel ^= 1;
        }
    }

    float bv[G];
#pragma unroll
    for (int g = 0; g < G; ++g) bv[g] = bias[oc0 + g * 16 + (lane & 15)];

    if constexpr (EPI == 0) {
        float* sc = (float*)(ldsAll + 41472 + wv * 2048);
#pragma unroll
        for (int rr = 0; rr < 4; ++rr) {
            const int yy = y0 + wv * 4 + rr;
#pragma unroll
            for (int g = 0; g < G; ++g) {
                f32x4 v = acc[rr][g];
#pragma unroll
                for (int j = 0; j < 4; ++j) {
                    v[j] += bv[g];
                    if (RELU) v[j] = fmaxf(v[j], 0.f);
                }
                *(f32x4*)&sc[(lane & 15) * 20 + ((lane >> 4) << 2)] = v;
                asm volatile("s_waitcnt lgkmcnt(0)" ::: "memory");
                f32x4 rd = *(const f32x4*)&sc[(lane >> 2) * 20 + ((lane & 3) << 2)];
                const int oc = oc0 + g * 16 + (lane >> 2);
                const int xs = x0 + ((lane & 3) << 2);
                if (yy < H && xs < W)
                    *(f32x4*)&outF[((size_t)(bb * COUT + oc)) * HW + yy * W + xs] = rd;
                asm volatile("s_waitcnt lgkmcnt(0)" ::: "memory");
            }
        }
    } else {
        unsigned short* sb = (unsigned short*)(ldsAll + 41472 + wv * 2048);
#pragma unroll
        for (int rr = 0; rr < 4; ++rr) {
            const int yy = y0 + wv * 4 + rr;
#pragma unroll
            for (int g = 0; g < G; ++g)
#pragma unroll
                for (int r2 = 0; r2 < 4; ++r2) {
                    float v = acc[rr][g][r2] + bv[g];
                    if (RELU) v = fmaxf(v, 0.f);
                    sb[(((lane >> 4) << 2) + r2) * OCB + g * 16 + (lane & 15)] = f2bf(v);
                }
            asm volatile("s_waitcnt lgkmcnt(0)" ::: "memory");
#pragma unroll
            for (int j = 0; j < OCB / 32; ++j) {
                int idx = j * 64 + lane;
                int px = idx / (OCB / 8), c8 = idx % (OCB / 8);
                short8 rd = *(const short8*)&sb[px * OCB + c8 * 8];
                int gx = x0 + px;
                if (yy < H && gx < W)
                    *(short8*)&outB[((size_t)(bb * PD + 1 + yy) * PD + 1 + gx) * COUT
                                    + oc0 + c8 * 8] = rd;
            }
            asm volatile("s_waitcnt lgkmcnt(0)" ::: "memory");
        }
    }
}

// ---------------------------------------------------------------------------
// conv2 64->4 + tanh*5 -> flow.  Reads padded NHWC bf16 hbuf (CP=64).
// Block 256 (16x16 px); LDS [c8][18][18][8ch] via GLL (linear dst, scattered src).
__global__ __launch_bounds__(256) void conv_flow_nhwc(
    const unsigned short* __restrict__ hbuf, const float* __restrict__ fw2,
    const float* __restrict__ fb2, float* __restrict__ flow, int B) {
    __shared__ __align__(16) char lds[41472 + 9216];
    unsigned short* s_in = (unsigned short*)lds;       // [8][18][18][8]
    float* s_w = (float*)(lds + 41472);                // [64][9][4oc]
    const int t = threadIdx.x;
    const int lane = t & 63, wv = t >> 6;
    const int b = blockIdx.z;
    const int y0 = blockIdx.y * 16, x0 = blockIdx.x * 16;   // padded coords
    const char* base = (const char*)hbuf + ((size_t)(b * PD + y0) * PD + x0) * 128;
    // stage 2592 16B chunks; chunk i: c8=i/324, row=(i%324)/18, col=i%18
#pragma unroll
    for (int g = 0; g < 10; ++g) {
        int idx = (wv * 10 + g) * 64 + lane;
        int c8 = idx / 324, rem = idx % 324;
        int row = rem / 18, col = rem % 18;
        GLL(base + ((size_t)row * PD + col) * 128 + c8 * 16,
            lds + (wv * 10 + g) * 1024);
    }
    if (wv == 3 && lane < 32) {
        int idx = 2560 + lane;
        int c8 = idx / 324, rem = idx % 324;
        int row = rem / 18, col = rem % 18;
        GLL(base + ((size_t)row * PD + col) * 128 + c8 * 16, lds + 40960);
    }
    // stage weights [ch][tap][oc]
#pragma unroll
    for (int i = 0; i < 9; ++i) {
        int u = i * 256 + t;
        int o = u & 3, tap = (u >> 2) % 9, ch = u / 36;
        s_w[(ch * 9 + tap) * 4 + o] = fw2[(size_t)(o * 64 + ch) * 9 + tap];
    }
    asm volatile("s_waitcnt vmcnt(0)" ::: "memory");
    __syncthreads();

    const int py = t >> 4, px = t & 15;
    float acc[4] = {fb2[0], fb2[1], fb2[2], fb2[3]};
#pragma unroll
    for (int c8 = 0; c8 < 8; ++c8)
#pragma unroll
        for (int ky = 0; ky < 3; ++ky)
#pragma unroll
            for (int kx = 0; kx < 3; ++kx) {
                short8 a8 = *(const short8*)&s_in[(((c8 * 18) + py + ky) * 18
                                                  + px + kx) * 8];
                const float* wp = &s_w[(c8 * 8 * 9 + (ky * 3 + kx)) * 4];
#pragma unroll
                for (int e = 0; e < 8; ++e) {
                    float a = bf2f((unsigned short)a8[e]);
                    float4 w4 = *(const float4*)(wp + e * 36);
                    acc[0] = fmaf(a, w4.x, acc[0]);
                    acc[1] = fmaf(a, w4.y, acc[1]);
                    acc[2] = fmaf(a, w4.z, acc[2]);
                    acc[3] = fmaf(a, w4.w, acc[3]);
                }
            }
    int h = y0 + py, w = x0 + px;
    if (h < H && w < W) {
#pragma unroll
        for (int o = 0; o < 4; ++o)
            flow[(size_t)(b * 4 + o) * HW + h * W + w] = tanhf(acc[o]) * 5.0f;
    }
}

// ---------------------------------------------------------------------------
// grid sample from cat (bf16 NHWC): chunk-major threads, coalesced in+out.
// q<16: img (cat ch 128+q*8) -> f2 ch q*8 ; q>=16: pts (cat ch (q-16)*8)
// -> f2 ch 128+(q-16)*8.
__global__ __launch_bounds__(256) void grid_sample_cat(
    const unsigned short* __restrict__ cat, const float* __restrict__ flow,
    unsigned short* __restrict__ f2, int B, int total) {
    int id = blockIdx.x * 256 + threadIdx.x;
    if (id >= total) return;                 // total = B*HW*32
    int q = id & 31; int pix = id >> 5;
    int w = pix % W; int r = pix / W;
    int h = r % H;  int b = r / H;
    const bool is_img = q < 16;
    const int j = is_img ? q : q - 16;
    const int fo = is_img ? 2 : 0;
    size_t fbase = (size_t)b * 4 * HW + h * W + w;
    float sx = (float)w + flow[fbase + (size_t)fo * HW];
    float sy = (float)h + flow[fbase + (size_t)(fo + 1) * HW];
    sx = fminf(fmaxf(sx, 0.f), (float)(W - 1));
    sy = fminf(fmaxf(sy, 0.f), (float)(H - 1));
    float x0f = floorf(sx), y0f = floorf(sy);
    float x1f = fminf(x0f + 1.f, (float)(W - 1));
    float y1f = fminf(y0f + 1.f, (float)(H - 1));
    float wx = sx - x0f, wy = sy - y0f;
    int x0 = (int)x0f, x1 = (int)x1f, y0 = (int)y0f, y1 = (int)y1f;
    float w00 = (1.f - wx) * (1.f - wy), w01 = wx * (1.f - wy);
    float w10 = (1.f - wx) * wy,         w11 = wx * wy;
    const unsigned short* cb0 = cat + (size_t)b * PD2 * 320
                                + (is_img ? 128 : 0) + j * 8;
    const short8 v00 = *(const short8*)&cb0[((size_t)(1 + y0) * PD + 1 + x0) * 320];
    const short8 v01 = *(const short8*)&cb0[((size_t)(1 + y0) * PD + 1 + x1) * 320];
    const short8 v10 = *(const short8*)&cb0[((size_t)(1 + y1) * PD + 1 + x0) * 320];
    const short8 v11 = *(const short8*)&cb0[((size_t)(1 + y1) * PD + 1 + x1) * 320];
    short8 pack;
#pragma unroll
    for (int e = 0; e < 8; ++e) {
        float v = bf2f((unsigned short)v00[e]) * w00 +
                  bf2f((unsigned short)v01[e]) * w01 +
                  bf2f((unsigned short)v10[e]) * w10 +
                  bf2f((unsigned short)v11[e]) * w11;
        pack[e] = (short)f2bf(v);
    }
    *(short8*)&f2[((size_t)(b * PD + 1 + h) * PD + 1 + w) * 256 +
                  (is_img ? 0 : 128) + j * 8] = pack;
}

// ---------------------------------------------------------------------------
extern "C" void kernel_launch(void* const* d_in, const int* in_sizes, int n_in,
                              void* d_out, int out_size, void* d_ws, size_t ws_size,
                              hipStream_t stream) {
    const float* pts  = (const float*)d_in[0];
    const float* img  = (const float*)d_in[1];
    const float* hm_p = (const float*)d_in[2];
    const float* hm_i = (const float*)d_in[3];
    const float* fw1  = (const float*)d_in[4];
    const float* fb1  = (const float*)d_in[5];
    const float* fw2  = (const float*)d_in[6];
    const float* fb2  = (const float*)d_in[7];
    const float* gw1  = (const float*)d_in[8];
    const float* gb1  = (const float*)d_in[9];
    const float* gw2  = (const float*)d_in[10];
    const float* gb2  = (const float*)d_in[11];
    char* ws = (char*)d_ws;
    const int B = in_sizes[0] / (128 * HW);   // 4

    unsigned short* cat  = (unsigned short*)(ws + OFF_CAT);
    unsigned short* f2   = (unsigned short*)(ws + OFF_F2);
    unsigned short* hbuf = (unsigned short*)(ws + OFF_HBUF);
    unsigned short* go   = (unsigned short*)(ws + OFF_GO);
    float* hpn   = (float*)(ws + OFF_HPN);
    float* hin   = (float*)(ws + OFF_HIN);
    float* flow  = (float*)(ws + OFF_FLOW);
    unsigned short* wf1  = (unsigned short*)(ws + OFF_WF1);
    unsigned short* wfg1 = (unsigned short*)(ws + OFF_WFG1);
    unsigned short* wfg2 = (unsigned short*)(ws + OFF_WFG2);

    // 1. weight frag transforms
    wfrag_kernel<1><<<180, 256, 0, stream>>>(fw1, wf1, 306, 4, 720);
    wfrag_kernel<0><<<288, 256, 0, stream>>>(gw1, wfg1, 256, 8, 1152);
    wfrag_kernel<0><<<144, 256, 0, stream>>>(gw2, wfg2, 128, 8, 576);
    // 2. cat halo zero + interior build
    {
        int tot = B * 5236 * 40;
        border_zero<<<(tot + 255) / 256, 256, 0, stream>>>(cat, 40, tot);
    }
    build_cat<<<B * 180, 192, 0, stream>>>(pts, img, cat);
    // 3. heatmaps + cost volumes (NHWC records)
    {
        dim3 grid(12, 12, 2 * B);
        prep_heatmaps<<<grid, 256, 0, stream>>>(hm_p, hm_i, hpn, hin, B);
    }
    int totc = B * HW;
    cost_volume_cat<<<(totc + 255) / 256, 256, 0, stream>>>(hpn, hin, cat, B, totc);
    // 4. hbuf halo zero (aliases hpn/hin, now dead) then conv1 -> bf16 NHWC
    {
        int tot = B * 5236 * 8;
        border_zero<<<(tot + 255) / 256, 256, 0, stream>>>(hbuf, 8, tot);
        dim3 grid(12, 12, 2 * B);
        conv_mfma<10, 64, 1, true, 32><<<grid, 256, 0, stream>>>(
            cat, wf1, fb1, nullptr, hbuf, B);
    }
    // 5. conv2 64->4 + tanh*5 -> flow
    {
        dim3 grid(12, 12, B);
        conv_flow_nhwc<<<grid, 256, 0, stream>>>(hbuf, fw2, fb2, flow, B);
    }
    // 6. halo zeros for f2/go
    {
        int tot = B * 5236 * 32;
        border_zero<<<(tot + 255) / 256, 256, 0, stream>>>(f2, 32, tot);
        int tot2 = B * 5236 * 16;
        border_zero<<<(tot2 + 255) / 256, 256, 0, stream>>>(go, 16, tot2);
    }
    // 7. grid sample (reads cat bf16) -> f2 interior
    int totg = B * HW * 32;
    grid_sample_cat<<<(totg + 255) / 256, 256, 0, stream>>>(cat, flow, f2, B, totg);
    // 8. g1 256->128 + relu -> go (padded NHWC bf16)
    {
        dim3 grid(12, 12, 2 * B);
        conv_mfma<8, 128, 1, true, 64><<<grid, 256, 0, stream>>>(
            f2, wfg1, gb1, nullptr, go, B);
    }
    // 9. g2 128->128 -> d_out (fp32 NCHW)
    {
        dim3 grid(12, 12, 2 * B);
        conv_mfma<4, 128, 0, false, 64><<<grid, 256, 0, stream>>>(
            go, wfg2, gb2, (float*)d_out, nullptr, B);
    }
}

// Round 5
// 658.253 us; speedup vs baseline: 4.3658x; 4.3658x over previous
//
#include <hip/hip_runtime.h>
#include <cstdint>

// ---------------------------------------------------------------------------
// SFA pipeline, round 5.
//   - MFMA convs (A bf16, W split hi+lo), pipelined weight prefetch (r3).
//   - grid_sample reads cat (bf16 NHWC), chunk-major: coalesced in+out (r4).
//   - conv1 emits bf16 NHWC; conv_flow rewritten spill-free: direct global
//     reads of 128B pixel records, weights in LDS, capped unrolling.
//   - heatmap path NHWC (12-float pixel records) for coalesced cost volume.
// ---------------------------------------------------------------------------

constexpr int H = 180, W = 180, HW = H * W;
constexpr int PD = 194, PD2 = PD * PD;          // padded pixel grid

typedef __attribute__((ext_vector_type(8))) short short8;
typedef __attribute__((ext_vector_type(4))) float f32x4;

// ---- workspace layout (bytes) ---------------------------------------------
constexpr size_t OFF_CAT  = 0;                          // ushort B*PD2*320 (96.3MB)
constexpr size_t OFF_F2   = 96348160;                   // ushort B*PD2*256 (77.1MB)
constexpr size_t R2       = OFF_F2 + 77078528;          // 173426688
constexpr size_t OFF_HPN  = R2;                         // float B*HW*12 (6.2MB)
constexpr size_t OFF_HIN  = R2 + 6220800;               // float B*HW*12
constexpr size_t OFF_HBUF = R2;                         // ushort B*PD2*64 (19.3MB, aliases hpn/hin)
constexpr size_t R3       = R2 + 19269632;              // 192696320
constexpr size_t OFF_GO   = R3;                         // ushort B*PD2*128 (38.5MB)
constexpr size_t OFF_FLOW = R3 + 38539264;              // float B*4*HW (2.07MB)
constexpr size_t OFF_WF1  = OFF_FLOW + 2073600;         // 233309184
constexpr size_t OFF_WFG1 = OFF_WF1 + 737280;
constexpr size_t OFF_WFG2 = OFF_WFG1 + 1179648;         // end ~235.8MB

__device__ __forceinline__ unsigned short f2bf(float x) {
    unsigned int u = __builtin_bit_cast(unsigned int, x);
    unsigned int r = (u + 0x7FFFu + ((u >> 16) & 1u)) >> 16;
    return (unsigned short)r;
}
__device__ __forceinline__ float bf2f(unsigned short b) {
    return __builtin_bit_cast(float, (unsigned int)b << 16);
}

#define GLL(SRC, DST) __builtin_amdgcn_global_load_lds(                        \
    (const __attribute__((address_space(1))) unsigned int*)(SRC),              \
    (__attribute__((address_space(3))) unsigned int*)(DST), 16, 0, 0)

// ---------------------------------------------------------------------------
// zero the halo border of a padded NHWC buffer (5236 border px per batch)
__global__ __launch_bounds__(256) void border_zero(unsigned short* __restrict__ buf,
                                                   int CPdiv8, int total) {
    int id = blockIdx.x * 256 + threadIdx.x;
    if (id >= total) return;
    int c8 = id % CPdiv8; int r = id / CPdiv8;
    int pi = r % 5236;    int b = r / 5236;
    int py, px;
    if (pi < 2716) { int ri = pi / 194; py = ri == 0 ? 0 : 180 + ri; px = pi % 194; }
    else { int j = pi - 2716; py = 1 + j / 14; int t = j % 14; px = t == 0 ? 0 : 180 + t; }
    short8 z = {0,0,0,0,0,0,0,0};
    *(short8*)&buf[((size_t)(b * PD + py) * PD + px) * (size_t)(CPdiv8 * 8) + c8 * 8] = z;
}

// ---------------------------------------------------------------------------
// build cat interior: pts -> ch 0..127, img -> ch 128..255 (perm; weights match)
__global__ __launch_bounds__(192) void build_cat(const float* __restrict__ pts,
                                                 const float* __restrict__ img,
                                                 unsigned short* __restrict__ cat) {
    int b = blockIdx.x / 180, h = blockIdx.x % 180;
    int t = threadIdx.x;
    if (t >= 180) return;
    unsigned short* pb = cat + ((size_t)(b * PD + 1 + h) * PD + (1 + t)) * 320;
    const float* ps = pts + (size_t)b * 128 * HW + h * W + t;
    const float* is = img + (size_t)b * 128 * HW + h * W + t;
#pragma unroll 4
    for (int v = 0; v < 16; ++v) {
        short8 o;
#pragma unroll
        for (int e = 0; e < 8; ++e) o[e] = (short)f2bf(ps[(size_t)(v * 8 + e) * HW]);
        *(short8*)&pb[v * 8] = o;
    }
#pragma unroll 4
    for (int v = 0; v < 16; ++v) {
        short8 o;
#pragma unroll
        for (int e = 0; e < 8; ++e) o[e] = (short)f2bf(is[(size_t)(v * 8 + e) * HW]);
        *(short8*)&pb[128 + v * 8] = o;
    }
}

// ---------------------------------------------------------------------------
// heatmap prep: LDS-tiled transpose; out = NHWC 12-float records [b][h][w][12]
__global__ __launch_bounds__(256) void prep_heatmaps(
    const float* __restrict__ hm_pts, const float* __restrict__ hm_img,
    float* __restrict__ hpn, float* __restrict__ hin, int B) {
    __shared__ float s[10][16][17];
    const int t = threadIdx.x;
    const int tsel = blockIdx.z & 1, b = blockIdx.z >> 1;
    const int h0 = blockIdx.y * 16, w0 = blockIdx.x * 16;
    const float* src = tsel ? hm_img : hm_pts;
    float* dst = tsel ? hin : hpn;
    {
        const int th = t & 15, tw = t >> 4;
        const int gh = h0 + th, gw = w0 + tw;
        if (gh < H && gw < W) {
#pragma unroll
            for (int c = 0; c < 10; ++c)
                s[c][tw][th] = src[((size_t)(b * 10 + c) * W + gw) * H + gh];
        }
    }
    __syncthreads();
    const int wq = t & 15, hq = t >> 4;
    const int gh = h0 + hq, gw = w0 + wq;
    if (gh >= H || gw >= W) return;
    float v[10]; float ss = 0.f;
#pragma unroll
    for (int c = 0; c < 10; ++c) {
        float x = s[c][wq][hq];
        float sg = 1.f / (1.f + expf(-x));
        v[c] = sg; ss += sg * sg;
    }
    float inv = 1.f / fmaxf(sqrtf(ss), 1e-12f);
    float* rec = dst + ((size_t)b * HW + gh * W + gw) * 12;
    float4 q0 = {v[0] * inv, v[1] * inv, v[2] * inv, v[3] * inv};
    float4 q1 = {v[4] * inv, v[5] * inv, v[6] * inv, v[7] * inv};
    float4 q2 = {v[8] * inv, v[9] * inv, 0.f, 0.f};
    *(float4*)rec = q0; *(float4*)(rec + 4) = q1; *(float4*)(rec + 8) = q2;
}

// ---------------------------------------------------------------------------
// cost volumes from NHWC records -> cat channels 256..305 (306..319 zero)
__global__ __launch_bounds__(256) void cost_volume_cat(
    const float* __restrict__ hpn, const float* __restrict__ hin,
    unsigned short* __restrict__ cat, int B, int total) {
    int id = blockIdx.x * 256 + threadIdx.x;
    if (id >= total) return;
    int w = id % W; int r = id / W;
    int h = r % H;  int b = r / H;
    const float* hpb = hpn + (size_t)b * HW * 12;
    const float* hib = hin + (size_t)b * HW * 12;
    float hp_l[10], hi_l[10];
    {
        const float* c0 = hpb + (size_t)(h * W + w) * 12;
        const float* c1 = hib + (size_t)(h * W + w) * 12;
        float4 a0 = *(const float4*)c0, a1 = *(const float4*)(c0 + 4);
        float4 a2 = *(const float4*)(c0 + 8);
        float4 b0 = *(const float4*)c1, b1 = *(const float4*)(c1 + 4);
        float4 b2 = *(const float4*)(c1 + 8);
        hp_l[0]=a0.x; hp_l[1]=a0.y; hp_l[2]=a0.z; hp_l[3]=a0.w;
        hp_l[4]=a1.x; hp_l[5]=a1.y; hp_l[6]=a1.z; hp_l[7]=a1.w;
        hp_l[8]=a2.x; hp_l[9]=a2.y;
        hi_l[0]=b0.x; hi_l[1]=b0.y; hi_l[2]=b0.z; hi_l[3]=b0.w;
        hi_l[4]=b1.x; hi_l[5]=b1.y; hi_l[6]=b1.z; hi_l[7]=b1.w;
        hi_l[8]=b2.x; hi_l[9]=b2.y;
    }
    unsigned pk[32];
#pragma unroll
    for (int j = 0; j < 32; ++j) pk[j] = 0;
#pragma unroll
    for (int dy = 0; dy < 5; ++dy)
#pragma unroll
        for (int dx = 0; dx < 5; ++dx) {
            const int k = dy * 5 + dx;
            int yy = h + dy - 2, xx = w + dx - 2;
            float ap = 0.f, ai = 0.f;
            if (yy >= 0 && yy < H && xx >= 0 && xx < W) {
                const float* n0 = hib + (size_t)(yy * W + xx) * 12;
                const float* n1 = hpb + (size_t)(yy * W + xx) * 12;
                float n0v[10], n1v[10];
                {
                    float4 u0=*(const float4*)n0, u1=*(const float4*)(n0+4);
                    float4 u2=*(const float4*)(n0+8);
                    float4 v0=*(const float4*)n1, v1=*(const float4*)(n1+4);
                    float4 v2=*(const float4*)(n1+8);
                    n0v[0]=u0.x;n0v[1]=u0.y;n0v[2]=u0.z;n0v[3]=u0.w;
                    n0v[4]=u1.x;n0v[5]=u1.y;n0v[6]=u1.z;n0v[7]=u1.w;
                    n0v[8]=u2.x;n0v[9]=u2.y;
                    n1v[0]=v0.x;n1v[1]=v0.y;n1v[2]=v0.z;n1v[3]=v0.w;
                    n1v[4]=v1.x;n1v[5]=v1.y;n1v[6]=v1.z;n1v[7]=v1.w;
                    n1v[8]=v2.x;n1v[9]=v2.y;
                }
#pragma unroll
                for (int c = 0; c < 10; ++c) {
                    ap = fmaf(hp_l[c], n0v[c], ap);
                    ai = fmaf(hi_l[c], n1v[c], ai);
                }
            }
            pk[k >> 1] |= (unsigned)f2bf(ap) << ((k & 1) * 16);
            const int kc = 25 + k;
            pk[kc >> 1] |= (unsigned)f2bf(ai) << ((kc & 1) * 16);
        }
    unsigned short* pb = cat + ((size_t)(b * PD + 1 + h) * PD + (1 + w)) * 320 + 256;
#pragma unroll
    for (int v = 0; v < 8; ++v) {
        uint4 q = {pk[v * 4], pk[v * 4 + 1], pk[v * 4 + 2], pk[v * 4 + 3]};
        *(uint4*)((char*)pb + v * 16) = q;
    }
}

// ---------------------------------------------------------------------------
// weight frag transform: w fp32 [oc][Cin][3][3] -> frag-linear bf16 hi/lo.
template <int MODE>
__global__ __launch_bounds__(256) void wfrag_kernel(const float* __restrict__ w,
                                                    unsigned short* __restrict__ wf,
                                                    int Cin, int nOg, int nfrag) {
    int t = blockIdx.x * 256 + threadIdx.x;
    int f = t >> 6, lane = t & 63;
    if (f >= nfrag) return;
    int part = f & 1; int r = f >> 1;
    int og = r % nOg; r /= nOg;
    int tap = r % 9;  int chunk = r / 9;
    int oc = og * 16 + (lane & 15);
    short8 out;
#pragma unroll
    for (int e = 0; e < 8; ++e) {
        int c = chunk * 32 + ((lane >> 4) << 3) + e;
        int rc = c;
        if (MODE == 1) {
            if (c < 128) rc = c;
            else if (c < 256) rc = c + 25;
            else if (c < 281) rc = c - 128;
            else rc = c;
        }
        float val = 0.f;
        if (rc < Cin && (MODE == 0 || c < 306))
            val = w[((size_t)oc * Cin + rc) * 9 + tap];
        unsigned short hi = f2bf(val);
        out[e] = (short)(part == 0 ? hi : f2bf(val - bf2f(hi)));
    }
    *(short8*)&wf[(size_t)f * 512 + lane * 8] = out;
}

// ---------------------------------------------------------------------------
// MFMA conv 3x3 SAME, software-pipelined weights (r3 core, unchanged).
template <int NCH, int COUT, int EPI, bool RELU, int OCB>
__global__ __launch_bounds__(256, 2) void conv_mfma(
    const unsigned short* __restrict__ act,  // padded NHWC, CP = NCH*32
    const unsigned short* __restrict__ wf,
    const float* __restrict__ bias,
    float* __restrict__ outF,                // EPI 0: fp32 NCHW
    unsigned short* __restrict__ outB,       // EPI 1: padded NHWC bf16 (CP=COUT)
    int Bn) {
    constexpr int CP = NCH * 32;
    constexpr int NOG = COUT / 16;
    constexpr int G = OCB / 16;
    __shared__ __align__(16) char ldsAll[2 * 20736 + 8192];

    const int tid = threadIdx.x;
    const int lane = tid & 63, wv = tid >> 6;
    const int zz = blockIdx.z;
    constexpr int NT = COUT / OCB;
    const int bb = zz / NT;
    const int oc0 = (zz % NT) * OCB;
    const int og0 = oc0 >> 4;
    const int y0 = blockIdx.y * 16, x0 = blockIdx.x * 16;

    const char* actB = (const char*)act + (size_t)bb * PD2 * CP * 2;

    unsigned soff[6];
#pragma unroll
    for (int i = 0; i < 6; ++i) {
        int idx = i * 256 + tid;
        int p = idx >> 2, q = idx & 3;
        int yy = p / 18, xx = p % 18;
        soff[i] = ((unsigned)((y0 + yy) * PD + (x0 + xx)) * CP + q * 8) * 2;
    }
    const int alane = (lane & 15) * 32 + ((lane >> 4) << 3);
    const unsigned short* wlane = wf + (size_t)og0 * 1024 + lane * 8;

    f32x4 acc[4][G];
#pragma unroll
    for (int i = 0; i < 4; ++i)
#pragma unroll
        for (int j = 0; j < G; ++j) acc[i][j] = (f32x4){0.f, 0.f, 0.f, 0.f};

    auto stage = [&](int chunk, int bsel) {
        unsigned co = (unsigned)chunk * 64;
#pragma unroll
        for (int i = 0; i < 5; ++i)
            GLL(actB + soff[i] + co,
                ldsAll + (size_t)bsel * 20736 + ((i << 8) + (wv << 6)) * 16);
        if (tid < 16)
            GLL(actB + soff[5] + co,
                ldsAll + (size_t)bsel * 20736 + ((5 << 8)) * 16);
    };
    auto loadW = [&](int idx, short8 (&dh)[G], short8 (&dl)[G]) {
        const unsigned short* p = wlane + (size_t)idx * NOG * 1024;
#pragma unroll
        for (int g = 0; g < G; ++g) {
            dh[g] = *(const short8*)(p + g * 1024);
            dl[g] = *(const short8*)(p + g * 1024 + 512);
        }
    };
    auto compTap = [&](int dy, int dx, const short8 (&bh)[G], const short8 (&bl)[G],
                       const unsigned short* tb) {
        __builtin_amdgcn_s_setprio(1);
#pragma unroll
        for (int rr = 0; rr < 4; ++rr) {
            const int yy = wv * 4 + rr + dy;
            short8 a = *(const short8*)(tb + (yy * 18 + dx) * 32 + alane);
#pragma unroll
            for (int g = 0; g < G; ++g) {
                asm("v_mfma_f32_16x16x32_bf16 %0, %1, %2, %0"
                    : "+v"(acc[rr][g]) : "v"(a), "v"(bh[g]));
                asm("v_mfma_f32_16x16x32_bf16 %0, %1, %2, %0"
                    : "+v"(acc[rr][g]) : "v"(a), "v"(bl[g]));
            }
        }
        __builtin_amdgcn_s_setprio(0);
    };

    short8 wh[2][G], wl[2][G];
    stage(0, 0);
    loadW(0, wh[0], wl[0]);
    asm volatile("s_waitcnt vmcnt(0)" ::: "memory");
    __syncthreads();

    int bsel = 0;
    for (int cp2 = 0; cp2 < NCH / 2; ++cp2) {
#pragma unroll
        for (int par = 0; par < 2; ++par) {
            const int chunk = cp2 * 2 + par;
            const unsigned short* tb = (const unsigned short*)ldsAll + bsel * 10368;
#pragma unroll
            for (int t = 0; t < 9; ++t) {
                const int cb = (t + par) & 1;
                if (t < 8) {
                    if (cb) loadW(chunk * 9 + t + 1, wh[0], wl[0]);
                    else    loadW(chunk * 9 + t + 1, wh[1], wl[1]);
                } else if (chunk + 1 < NCH) {
                    if (cb) loadW((chunk + 1) * 9, wh[0], wl[0]);
                    else    loadW((chunk + 1) * 9, wh[1], wl[1]);
                }
                if (t == 0 && chunk + 1 < NCH) stage(chunk + 1, bsel ^ 1);
                if (cb) compTap(t / 3, t % 3, wh[1], wl[1], tb);
                else    compTap(t / 3, t % 3, wh[0], wl[0], tb);
            }
            asm volatile("s_waitcnt vmcnt(0)" ::: "memory");
            __syncthreads();
            bsel ^= 1;
        }
    }

    float bv[G];
#pragma unroll
    for (int g = 0; g < G; ++g) bv[g] = bias[oc0 + g * 16 + (lane & 15)];

    if constexpr (EPI == 0) {
        float* sc = (float*)(ldsAll + 41472 + wv * 2048);
#pragma unroll
        for (int rr = 0; rr < 4; ++rr) {
            const int yy = y0 + wv * 4 + rr;
#pragma unroll
            for (int g = 0; g < G; ++g) {
                f32x4 v = acc[rr][g];
#pragma unroll
                for (int j = 0; j < 4; ++j) {
                    v[j] += bv[g];
                    if (RELU) v[j] = fmaxf(v[j], 0.f);
                }
                *(f32x4*)&sc[(lane & 15) * 20 + ((lane >> 4) << 2)] = v;
                asm volatile("s_waitcnt lgkmcnt(0)" ::: "memory");
                f32x4 rd = *(const f32x4*)&sc[(lane >> 2) * 20 + ((lane & 3) << 2)];
                const int oc = oc0 + g * 16 + (lane >> 2);
                const int xs = x0 + ((lane & 3) << 2);
                if (yy < H && xs < W)
                    *(f32x4*)&outF[((size_t)(bb * COUT + oc)) * HW + yy * W + xs] = rd;
                asm volatile("s_waitcnt lgkmcnt(0)" ::: "memory");
            }
        }
    } else {
        unsigned short* sb = (unsigned short*)(ldsAll + 41472 + wv * 2048);
#pragma unroll
        for (int rr = 0; rr < 4; ++rr) {
            const int yy = y0 + wv * 4 + rr;
#pragma unroll
            for (int g = 0; g < G; ++g)
#pragma unroll
                for (int r2 = 0; r2 < 4; ++r2) {
                    float v = acc[rr][g][r2] + bv[g];
                    if (RELU) v = fmaxf(v, 0.f);
                    sb[(((lane >> 4) << 2) + r2) * OCB + g * 16 + (lane & 15)] = f2bf(v);
                }
            asm volatile("s_waitcnt lgkmcnt(0)" ::: "memory");
#pragma unroll
            for (int j = 0; j < OCB / 32; ++j) {
                int idx = j * 64 + lane;
                int px = idx / (OCB / 8), c8 = idx % (OCB / 8);
                short8 rd = *(const short8*)&sb[px * OCB + c8 * 8];
                int gx = x0 + px;
                if (yy < H && gx < W)
                    *(short8*)&outB[((size_t)(bb * PD + 1 + yy) * PD + 1 + gx) * COUT
                                    + oc0 + c8 * 8] = rd;
            }
            asm volatile("s_waitcnt lgkmcnt(0)" ::: "memory");
        }
    }
}

// ---------------------------------------------------------------------------
// conv2 64->4 + tanh*5 -> flow.  Reads padded NHWC bf16 hbuf (CP=64).
// Spill-free: one pixel per thread, direct coalesced 16B global reads
// (neighbor overlap served by L2), weights broadcast from LDS, c8 loop
// NOT unrolled to cap the live set (~90 VGPR).
__global__ __launch_bounds__(256) void conv_flow_lite(
    const unsigned short* __restrict__ hbuf, const float* __restrict__ fw2,
    const float* __restrict__ fb2, float* __restrict__ flow, int B) {
    __shared__ float s_w[2304];              // [ch][tap][oc] = 64*9*4
    for (int u = threadIdx.x; u < 2304; u += 256) {
        int o = u & 3, tap = (u >> 2) % 9, ch = u / 36;
        s_w[u] = fw2[(size_t)(o * 64 + ch) * 9 + tap];
    }
    __syncthreads();
    const int t = threadIdx.x;
    const int py = t >> 4, px = t & 15;
    const int b = blockIdx.z;
    const int y0 = blockIdx.y * 16, x0 = blockIdx.x * 16;   // padded coords
    const unsigned short* base = hbuf + ((size_t)(b * PD + y0) * PD + x0) * 64;
    float acc[4] = {fb2[0], fb2[1], fb2[2], fb2[3]};
#pragma unroll 1
    for (int c8 = 0; c8 < 8; ++c8) {
#pragma unroll
        for (int ky = 0; ky < 3; ++ky)
#pragma unroll
            for (int kx = 0; kx < 3; ++kx) {
                short8 a8 = *(const short8*)&base[((size_t)(py + ky) * PD
                                                  + px + kx) * 64 + c8 * 8];
                const float* wp = &s_w[(c8 * 8 * 9 + ky * 3 + kx) * 4];
#pragma unroll
                for (int e = 0; e < 8; ++e) {
                    float a = bf2f((unsigned short)a8[e]);
                    float4 w4 = *(const float4*)(wp + e * 36);
                    acc[0] = fmaf(a, w4.x, acc[0]);
                    acc[1] = fmaf(a, w4.y, acc[1]);
                    acc[2] = fmaf(a, w4.z, acc[2]);
                    acc[3] = fmaf(a, w4.w, acc[3]);
                }
            }
    }
    int h = y0 + py, w = x0 + px;
    if (h < H && w < W) {
#pragma unroll
        for (int o = 0; o < 4; ++o)
            flow[(size_t)(b * 4 + o) * HW + h * W + w] = tanhf(acc[o]) * 5.0f;
    }
}

// ---------------------------------------------------------------------------
// grid sample from cat (bf16 NHWC): chunk-major threads, coalesced in+out.
__global__ __launch_bounds__(256) void grid_sample_cat(
    const unsigned short* __restrict__ cat, const float* __restrict__ flow,
    unsigned short* __restrict__ f2, int B, int total) {
    int id = blockIdx.x * 256 + threadIdx.x;
    if (id >= total) return;                 // total = B*HW*32
    int q = id & 31; int pix = id >> 5;
    int w = pix % W; int r = pix / W;
    int h = r % H;  int b = r / H;
    const bool is_img = q < 16;
    const int j = is_img ? q : q - 16;
    const int fo = is_img ? 2 : 0;
    size_t fbase = (size_t)b * 4 * HW + h * W + w;
    float sx = (float)w + flow[fbase + (size_t)fo * HW];
    float sy = (float)h + flow[fbase + (size_t)(fo + 1) * HW];
    sx = fminf(fmaxf(sx, 0.f), (float)(W - 1));
    sy = fminf(fmaxf(sy, 0.f), (float)(H - 1));
    float x0f = floorf(sx), y0f = floorf(sy);
    float x1f = fminf(x0f + 1.f, (float)(W - 1));
    float y1f = fminf(y0f + 1.f, (float)(H - 1));
    float wx = sx - x0f, wy = sy - y0f;
    int x0 = (int)x0f, x1 = (int)x1f, y0 = (int)y0f, y1 = (int)y1f;
    float w00 = (1.f - wx) * (1.f - wy), w01 = wx * (1.f - wy);
    float w10 = (1.f - wx) * wy,         w11 = wx * wy;
    const unsigned short* cb0 = cat + (size_t)b * PD2 * 320
                                + (is_img ? 128 : 0) + j * 8;
    const short8 v00 = *(const short8*)&cb0[((size_t)(1 + y0) * PD + 1 + x0) * 320];
    const short8 v01 = *(const short8*)&cb0[((size_t)(1 + y0) * PD + 1 + x1) * 320];
    const short8 v10 = *(const short8*)&cb0[((size_t)(1 + y1) * PD + 1 + x0) * 320];
    const short8 v11 = *(const short8*)&cb0[((size_t)(1 + y1) * PD + 1 + x1) * 320];
    short8 pack;
#pragma unroll
    for (int e = 0; e < 8; ++e) {
        float v = bf2f((unsigned short)v00[e]) * w00 +
                  bf2f((unsigned short)v01[e]) * w01 +
                  bf2f((unsigned short)v10[e]) * w10 +
                  bf2f((unsigned short)v11[e]) * w11;
        pack[e] = (short)f2bf(v);
    }
    *(short8*)&f2[((size_t)(b * PD + 1 + h) * PD + 1 + w) * 256 +
                  (is_img ? 0 : 128) + j * 8] = pack;
}

// ---------------------------------------------------------------------------
extern "C" void kernel_launch(void* const* d_in, const int* in_sizes, int n_in,
                              void* d_out, int out_size, void* d_ws, size_t ws_size,
                              hipStream_t stream) {
    const float* pts  = (const float*)d_in[0];
    const float* img  = (const float*)d_in[1];
    const float* hm_p = (const float*)d_in[2];
    const float* hm_i = (const float*)d_in[3];
    const float* fw1  = (const float*)d_in[4];
    const float* fb1  = (const float*)d_in[5];
    const float* fw2  = (const float*)d_in[6];
    const float* fb2  = (const float*)d_in[7];
    const float* gw1  = (const float*)d_in[8];
    const float* gb1  = (const float*)d_in[9];
    const float* gw2  = (const float*)d_in[10];
    const float* gb2  = (const float*)d_in[11];
    char* ws = (char*)d_ws;
    const int B = in_sizes[0] / (128 * HW);   // 4

    unsigned short* cat  = (unsigned short*)(ws + OFF_CAT);
    unsigned short* f2   = (unsigned short*)(ws + OFF_F2);
    unsigned short* hbuf = (unsigned short*)(ws + OFF_HBUF);
    unsigned short* go   = (unsigned short*)(ws + OFF_GO);
    float* hpn   = (float*)(ws + OFF_HPN);
    float* hin   = (float*)(ws + OFF_HIN);
    float* flow  = (float*)(ws + OFF_FLOW);
    unsigned short* wf1  = (unsigned short*)(ws + OFF_WF1);
    unsigned short* wfg1 = (unsigned short*)(ws + OFF_WFG1);
    unsigned short* wfg2 = (unsigned short*)(ws + OFF_WFG2);

    // 1. weight frag transforms
    wfrag_kernel<1><<<180, 256, 0, stream>>>(fw1, wf1, 306, 4, 720);
    wfrag_kernel<0><<<288, 256, 0, stream>>>(gw1, wfg1, 256, 8, 1152);
    wfrag_kernel<0><<<144, 256, 0, stream>>>(gw2, wfg2, 128, 8, 576);
    // 2. cat halo zero + interior build
    {
        int tot = B * 5236 * 40;
        border_zero<<<(tot + 255) / 256, 256, 0, stream>>>(cat, 40, tot);
    }
    build_cat<<<B * 180, 192, 0, stream>>>(pts, img, cat);
    // 3. heatmaps + cost volumes (NHWC records)
    {
        dim3 grid(12, 12, 2 * B);
        prep_heatmaps<<<grid, 256, 0, stream>>>(hm_p, hm_i, hpn, hin, B);
    }
    int totc = B * HW;
    cost_volume_cat<<<(totc + 255) / 256, 256, 0, stream>>>(hpn, hin, cat, B, totc);
    // 4. hbuf halo zero (aliases hpn/hin, now dead) then conv1 -> bf16 NHWC
    {
        int tot = B * 5236 * 8;
        border_zero<<<(tot + 255) / 256, 256, 0, stream>>>(hbuf, 8, tot);
        dim3 grid(12, 12, 2 * B);
        conv_mfma<10, 64, 1, true, 32><<<grid, 256, 0, stream>>>(
            cat, wf1, fb1, nullptr, hbuf, B);
    }
    // 5. conv2 64->4 + tanh*5 -> flow (spill-free lite kernel)
    {
        dim3 grid(12, 12, B);
        conv_flow_lite<<<grid, 256, 0, stream>>>(hbuf, fw2, fb2, flow, B);
    }
    // 6. halo zeros for f2/go
    {
        int tot = B * 5236 * 32;
        border_zero<<<(tot + 255) / 256, 256, 0, stream>>>(f2, 32, tot);
        int tot2 = B * 5236 * 16;
        border_zero<<<(tot2 + 255) / 256, 256, 0, stream>>>(go, 16, tot2);
    }
    // 7. grid sample (reads cat bf16) -> f2 interior
    int totg = B * HW * 32;
    grid_sample_cat<<<(totg + 255) / 256, 256, 0, stream>>>(cat, flow, f2, B, totg);
    // 8. g1 256->128 + relu -> go (padded NHWC bf16)
    {
        dim3 grid(12, 12, 2 * B);
        conv_mfma<8, 128, 1, true, 64><<<grid, 256, 0, stream>>>(
            f2, wfg1, gb1, nullptr, go, B);
    }
    // 9. g2 128->128 -> d_out (fp32 NCHW)
    {
        dim3 grid(12, 12, 2 * B);
        conv_mfma<4, 128, 0, false, 64><<<grid, 256, 0, stream>>>(
            go, wfg2, gb2, (float*)d_out, nullptr, B);
    }
}

// Round 6
// 653.484 us; speedup vs baseline: 4.3977x; 1.0073x over previous
//
#include <hip/hip_runtime.h>
#include <cstdint>

// ---------------------------------------------------------------------------
// SFA pipeline, round 6.
//   r5 + LDS XOR-swizzle (T2 / rule #21) in conv_mfma:
//   A-tile chunk (p,q) stored at slot q^((p>>1)&3) via pre-swizzled GLOBAL
//   source (GLL dest stays linear), read with the same XOR -> 2-way (free)
//   instead of 4-way bank conflict on ds_read_b128.
// ---------------------------------------------------------------------------

constexpr int H = 180, W = 180, HW = H * W;
constexpr int PD = 194, PD2 = PD * PD;          // padded pixel grid

typedef __attribute__((ext_vector_type(8))) short short8;
typedef __attribute__((ext_vector_type(4))) float f32x4;

// ---- workspace layout (bytes) ---------------------------------------------
constexpr size_t OFF_CAT  = 0;                          // ushort B*PD2*320 (96.3MB)
constexpr size_t OFF_F2   = 96348160;                   // ushort B*PD2*256 (77.1MB)
constexpr size_t R2       = OFF_F2 + 77078528;          // 173426688
constexpr size_t OFF_HPN  = R2;                         // float B*HW*12 (6.2MB)
constexpr size_t OFF_HIN  = R2 + 6220800;               // float B*HW*12
constexpr size_t OFF_HBUF = R2;                         // ushort B*PD2*64 (19.3MB, aliases hpn/hin)
constexpr size_t R3       = R2 + 19269632;              // 192696320
constexpr size_t OFF_GO   = R3;                         // ushort B*PD2*128 (38.5MB)
constexpr size_t OFF_FLOW = R3 + 38539264;              // float B*4*HW (2.07MB)
constexpr size_t OFF_WF1  = OFF_FLOW + 2073600;         // 233309184
constexpr size_t OFF_WFG1 = OFF_WF1 + 737280;
constexpr size_t OFF_WFG2 = OFF_WFG1 + 1179648;         // end ~235.8MB

__device__ __forceinline__ unsigned short f2bf(float x) {
    unsigned int u = __builtin_bit_cast(unsigned int, x);
    unsigned int r = (u + 0x7FFFu + ((u >> 16) & 1u)) >> 16;
    return (unsigned short)r;
}
__device__ __forceinline__ float bf2f(unsigned short b) {
    return __builtin_bit_cast(float, (unsigned int)b << 16);
}

#define GLL(SRC, DST) __builtin_amdgcn_global_load_lds(                        \
    (const __attribute__((address_space(1))) unsigned int*)(SRC),              \
    (__attribute__((address_space(3))) unsigned int*)(DST), 16, 0, 0)

// ---------------------------------------------------------------------------
// zero the halo border of a padded NHWC buffer (5236 border px per batch)
__global__ __launch_bounds__(256) void border_zero(unsigned short* __restrict__ buf,
                                                   int CPdiv8, int total) {
    int id = blockIdx.x * 256 + threadIdx.x;
    if (id >= total) return;
    int c8 = id % CPdiv8; int r = id / CPdiv8;
    int pi = r % 5236;    int b = r / 5236;
    int py, px;
    if (pi < 2716) { int ri = pi / 194; py = ri == 0 ? 0 : 180 + ri; px = pi % 194; }
    else { int j = pi - 2716; py = 1 + j / 14; int t = j % 14; px = t == 0 ? 0 : 180 + t; }
    short8 z = {0,0,0,0,0,0,0,0};
    *(short8*)&buf[((size_t)(b * PD + py) * PD + px) * (size_t)(CPdiv8 * 8) + c8 * 8] = z;
}

// ---------------------------------------------------------------------------
// build cat interior: pts -> ch 0..127, img -> ch 128..255 (perm; weights match)
__global__ __launch_bounds__(192) void build_cat(const float* __restrict__ pts,
                                                 const float* __restrict__ img,
                                                 unsigned short* __restrict__ cat) {
    int b = blockIdx.x / 180, h = blockIdx.x % 180;
    int t = threadIdx.x;
    if (t >= 180) return;
    unsigned short* pb = cat + ((size_t)(b * PD + 1 + h) * PD + (1 + t)) * 320;
    const float* ps = pts + (size_t)b * 128 * HW + h * W + t;
    const float* is = img + (size_t)b * 128 * HW + h * W + t;
#pragma unroll 4
    for (int v = 0; v < 16; ++v) {
        short8 o;
#pragma unroll
        for (int e = 0; e < 8; ++e) o[e] = (short)f2bf(ps[(size_t)(v * 8 + e) * HW]);
        *(short8*)&pb[v * 8] = o;
    }
#pragma unroll 4
    for (int v = 0; v < 16; ++v) {
        short8 o;
#pragma unroll
        for (int e = 0; e < 8; ++e) o[e] = (short)f2bf(is[(size_t)(v * 8 + e) * HW]);
        *(short8*)&pb[128 + v * 8] = o;
    }
}

// ---------------------------------------------------------------------------
// heatmap prep: LDS-tiled transpose; out = NHWC 12-float records [b][h][w][12]
__global__ __launch_bounds__(256) void prep_heatmaps(
    const float* __restrict__ hm_pts, const float* __restrict__ hm_img,
    float* __restrict__ hpn, float* __restrict__ hin, int B) {
    __shared__ float s[10][16][17];
    const int t = threadIdx.x;
    const int tsel = blockIdx.z & 1, b = blockIdx.z >> 1;
    const int h0 = blockIdx.y * 16, w0 = blockIdx.x * 16;
    const float* src = tsel ? hm_img : hm_pts;
    float* dst = tsel ? hin : hpn;
    {
        const int th = t & 15, tw = t >> 4;
        const int gh = h0 + th, gw = w0 + tw;
        if (gh < H && gw < W) {
#pragma unroll
            for (int c = 0; c < 10; ++c)
                s[c][tw][th] = src[((size_t)(b * 10 + c) * W + gw) * H + gh];
        }
    }
    __syncthreads();
    const int wq = t & 15, hq = t >> 4;
    const int gh = h0 + hq, gw = w0 + wq;
    if (gh >= H || gw >= W) return;
    float v[10]; float ss = 0.f;
#pragma unroll
    for (int c = 0; c < 10; ++c) {
        float x = s[c][wq][hq];
        float sg = 1.f / (1.f + expf(-x));
        v[c] = sg; ss += sg * sg;
    }
    float inv = 1.f / fmaxf(sqrtf(ss), 1e-12f);
    float* rec = dst + ((size_t)b * HW + gh * W + gw) * 12;
    float4 q0 = {v[0] * inv, v[1] * inv, v[2] * inv, v[3] * inv};
    float4 q1 = {v[4] * inv, v[5] * inv, v[6] * inv, v[7] * inv};
    float4 q2 = {v[8] * inv, v[9] * inv, 0.f, 0.f};
    *(float4*)rec = q0; *(float4*)(rec + 4) = q1; *(float4*)(rec + 8) = q2;
}

// ---------------------------------------------------------------------------
// cost volumes from NHWC records -> cat channels 256..305 (306..319 zero)
__global__ __launch_bounds__(256) void cost_volume_cat(
    const float* __restrict__ hpn, const float* __restrict__ hin,
    unsigned short* __restrict__ cat, int B, int total) {
    int id = blockIdx.x * 256 + threadIdx.x;
    if (id >= total) return;
    int w = id % W; int r = id / W;
    int h = r % H;  int b = r / H;
    const float* hpb = hpn + (size_t)b * HW * 12;
    const float* hib = hin + (size_t)b * HW * 12;
    float hp_l[10], hi_l[10];
    {
        const float* c0 = hpb + (size_t)(h * W + w) * 12;
        const float* c1 = hib + (size_t)(h * W + w) * 12;
        float4 a0 = *(const float4*)c0, a1 = *(const float4*)(c0 + 4);
        float4 a2 = *(const float4*)(c0 + 8);
        float4 b0 = *(const float4*)c1, b1 = *(const float4*)(c1 + 4);
        float4 b2 = *(const float4*)(c1 + 8);
        hp_l[0]=a0.x; hp_l[1]=a0.y; hp_l[2]=a0.z; hp_l[3]=a0.w;
        hp_l[4]=a1.x; hp_l[5]=a1.y; hp_l[6]=a1.z; hp_l[7]=a1.w;
        hp_l[8]=a2.x; hp_l[9]=a2.y;
        hi_l[0]=b0.x; hi_l[1]=b0.y; hi_l[2]=b0.z; hi_l[3]=b0.w;
        hi_l[4]=b1.x; hi_l[5]=b1.y; hi_l[6]=b1.z; hi_l[7]=b1.w;
        hi_l[8]=b2.x; hi_l[9]=b2.y;
    }
    unsigned pk[32];
#pragma unroll
    for (int j = 0; j < 32; ++j) pk[j] = 0;
#pragma unroll
    for (int dy = 0; dy < 5; ++dy)
#pragma unroll
        for (int dx = 0; dx < 5; ++dx) {
            const int k = dy * 5 + dx;
            int yy = h + dy - 2, xx = w + dx - 2;
            float ap = 0.f, ai = 0.f;
            if (yy >= 0 && yy < H && xx >= 0 && xx < W) {
                const float* n0 = hib + (size_t)(yy * W + xx) * 12;
                const float* n1 = hpb + (size_t)(yy * W + xx) * 12;
                float n0v[10], n1v[10];
                {
                    float4 u0=*(const float4*)n0, u1=*(const float4*)(n0+4);
                    float4 u2=*(const float4*)(n0+8);
                    float4 v0=*(const float4*)n1, v1=*(const float4*)(n1+4);
                    float4 v2=*(const float4*)(n1+8);
                    n0v[0]=u0.x;n0v[1]=u0.y;n0v[2]=u0.z;n0v[3]=u0.w;
                    n0v[4]=u1.x;n0v[5]=u1.y;n0v[6]=u1.z;n0v[7]=u1.w;
                    n0v[8]=u2.x;n0v[9]=u2.y;
                    n1v[0]=v0.x;n1v[1]=v0.y;n1v[2]=v0.z;n1v[3]=v0.w;
                    n1v[4]=v1.x;n1v[5]=v1.y;n1v[6]=v1.z;n1v[7]=v1.w;
                    n1v[8]=v2.x;n1v[9]=v2.y;
                }
#pragma unroll
                for (int c = 0; c < 10; ++c) {
                    ap = fmaf(hp_l[c], n0v[c], ap);
                    ai = fmaf(hi_l[c], n1v[c], ai);
                }
            }
            pk[k >> 1] |= (unsigned)f2bf(ap) << ((k & 1) * 16);
            const int kc = 25 + k;
            pk[kc >> 1] |= (unsigned)f2bf(ai) << ((kc & 1) * 16);
        }
    unsigned short* pb = cat + ((size_t)(b * PD + 1 + h) * PD + (1 + w)) * 320 + 256;
#pragma unroll
    for (int v = 0; v < 8; ++v) {
        uint4 q = {pk[v * 4], pk[v * 4 + 1], pk[v * 4 + 2], pk[v * 4 + 3]};
        *(uint4*)((char*)pb + v * 16) = q;
    }
}

// ---------------------------------------------------------------------------
// weight frag transform: w fp32 [oc][Cin][3][3] -> frag-linear bf16 hi/lo.
template <int MODE>
__global__ __launch_bounds__(256) void wfrag_kernel(const float* __restrict__ w,
                                                    unsigned short* __restrict__ wf,
                                                    int Cin, int nOg, int nfrag) {
    int t = blockIdx.x * 256 + threadIdx.x;
    int f = t >> 6, lane = t & 63;
    if (f >= nfrag) return;
    int part = f & 1; int r = f >> 1;
    int og = r % nOg; r /= nOg;
    int tap = r % 9;  int chunk = r / 9;
    int oc = og * 16 + (lane & 15);
    short8 out;
#pragma unroll
    for (int e = 0; e < 8; ++e) {
        int c = chunk * 32 + ((lane >> 4) << 3) + e;
        int rc = c;
        if (MODE == 1) {
            if (c < 128) rc = c;
            else if (c < 256) rc = c + 25;
            else if (c < 281) rc = c - 128;
            else rc = c;
        }
        float val = 0.f;
        if (rc < Cin && (MODE == 0 || c < 306))
            val = w[((size_t)oc * Cin + rc) * 9 + tap];
        unsigned short hi = f2bf(val);
        out[e] = (short)(part == 0 ? hi : f2bf(val - bf2f(hi)));
    }
    *(short8*)&wf[(size_t)f * 512 + lane * 8] = out;
}

// ---------------------------------------------------------------------------
// MFMA conv 3x3 SAME, software-pipelined weights + XOR-swizzled A-tile LDS.
// A-tile layout: chunk (p,q) [p = pixel 0..323, q = 16B channel-quarter]
// lives at LDS slot (p, q ^ ((p>>1)&3)).  Write side: GLL linear dst with
// inverse-permuted GLOBAL source.  Read side: same XOR.  -> 2-way (free).
template <int NCH, int COUT, int EPI, bool RELU, int OCB>
__global__ __launch_bounds__(256, 2) void conv_mfma(
    const unsigned short* __restrict__ act,  // padded NHWC, CP = NCH*32
    const unsigned short* __restrict__ wf,
    const float* __restrict__ bias,
    float* __restrict__ outF,                // EPI 0: fp32 NCHW
    unsigned short* __restrict__ outB,       // EPI 1: padded NHWC bf16 (CP=COUT)
    int Bn) {
    constexpr int CP = NCH * 32;
    constexpr int NOG = COUT / 16;
    constexpr int G = OCB / 16;
    __shared__ __align__(16) char ldsAll[2 * 20736 + 8192];

    const int tid = threadIdx.x;
    const int lane = tid & 63, wv = tid >> 6;
    const int zz = blockIdx.z;
    constexpr int NT = COUT / OCB;
    const int bb = zz / NT;
    const int oc0 = (zz % NT) * OCB;
    const int og0 = oc0 >> 4;
    const int y0 = blockIdx.y * 16, x0 = blockIdx.x * 16;

    const char* actB = (const char*)act + (size_t)bb * PD2 * CP * 2;

    // staging source offsets (bytes in batch) with inverse swizzle:
    // LDS slot idx=(p,qs) receives global chunk (p, qs ^ ((p>>1)&3)).
    unsigned soff[6];
#pragma unroll
    for (int i = 0; i < 6; ++i) {
        int idx = i * 256 + tid;
        int p = idx >> 2, qs = idx & 3;
        int q = qs ^ ((p >> 1) & 3);
        int yy = p / 18, xx = p % 18;
        soff[i] = ((unsigned)((y0 + yy) * PD + (x0 + xx)) * CP + q * 8) * 2;
    }
    const int mlane = lane & 15, qlane = lane >> 4;
    const unsigned short* wlane = wf + (size_t)og0 * 1024 + lane * 8;

    f32x4 acc[4][G];
#pragma unroll
    for (int i = 0; i < 4; ++i)
#pragma unroll
        for (int j = 0; j < G; ++j) acc[i][j] = (f32x4){0.f, 0.f, 0.f, 0.f};

    auto stage = [&](int chunk, int bsel) {
        unsigned co = (unsigned)chunk * 64;
#pragma unroll
        for (int i = 0; i < 5; ++i)
            GLL(actB + soff[i] + co,
                ldsAll + (size_t)bsel * 20736 + ((i << 8) + (wv << 6)) * 16);
        if (tid < 16)
            GLL(actB + soff[5] + co,
                ldsAll + (size_t)bsel * 20736 + ((5 << 8)) * 16);
    };
    auto loadW = [&](int idx, short8 (&dh)[G], short8 (&dl)[G]) {
        const unsigned short* p = wlane + (size_t)idx * NOG * 1024;
#pragma unroll
        for (int g = 0; g < G; ++g) {
            dh[g] = *(const short8*)(p + g * 1024);
            dl[g] = *(const short8*)(p + g * 1024 + 512);
        }
    };
    auto compTap = [&](int dy, int dx, const short8 (&bh)[G], const short8 (&bl)[G],
                       const unsigned short* tb) {
        __builtin_amdgcn_s_setprio(1);
#pragma unroll
        for (int rr = 0; rr < 4; ++rr) {
            const int pr = (wv * 4 + rr + dy) * 18 + dx + mlane;   // pixel slot
            const int qs = qlane ^ ((pr >> 1) & 3);                // swizzled read
            short8 a = *(const short8*)(tb + pr * 32 + (qs << 3));
#pragma unroll
            for (int g = 0; g < G; ++g) {
                asm("v_mfma_f32_16x16x32_bf16 %0, %1, %2, %0"
                    : "+v"(acc[rr][g]) : "v"(a), "v"(bh[g]));
                asm("v_mfma_f32_16x16x32_bf16 %0, %1, %2, %0"
                    : "+v"(acc[rr][g]) : "v"(a), "v"(bl[g]));
            }
        }
        __builtin_amdgcn_s_setprio(0);
    };

    short8 wh[2][G], wl[2][G];
    stage(0, 0);
    loadW(0, wh[0], wl[0]);
    asm volatile("s_waitcnt vmcnt(0)" ::: "memory");
    __syncthreads();

    int bsel = 0;
    for (int cp2 = 0; cp2 < NCH / 2; ++cp2) {
#pragma unroll
        for (int par = 0; par < 2; ++par) {
            const int chunk = cp2 * 2 + par;
            const unsigned short* tb = (const unsigned short*)ldsAll + bsel * 10368;
#pragma unroll
            for (int t = 0; t < 9; ++t) {
                const int cb = (t + par) & 1;
                if (t < 8) {
                    if (cb) loadW(chunk * 9 + t + 1, wh[0], wl[0]);
                    else    loadW(chunk * 9 + t + 1, wh[1], wl[1]);
                } else if (chunk + 1 < NCH) {
                    if (cb) loadW((chunk + 1) * 9, wh[0], wl[0]);
                    else    loadW((chunk + 1) * 9, wh[1], wl[1]);
                }
                if (t == 0 && chunk + 1 < NCH) stage(chunk + 1, bsel ^ 1);
                if (cb) compTap(t / 3, t % 3, wh[1], wl[1], tb);
                else    compTap(t / 3, t % 3, wh[0], wl[0], tb);
            }
            asm volatile("s_waitcnt vmcnt(0)" ::: "memory");
            __syncthreads();
            bsel ^= 1;
        }
    }

    float bv[G];
#pragma unroll
    for (int g = 0; g < G; ++g) bv[g] = bias[oc0 + g * 16 + (lane & 15)];

    if constexpr (EPI == 0) {
        float* sc = (float*)(ldsAll + 41472 + wv * 2048);
#pragma unroll
        for (int rr = 0; rr < 4; ++rr) {
            const int yy = y0 + wv * 4 + rr;
#pragma unroll
            for (int g = 0; g < G; ++g) {
                f32x4 v = acc[rr][g];
#pragma unroll
                for (int j = 0; j < 4; ++j) {
                    v[j] += bv[g];
                    if (RELU) v[j] = fmaxf(v[j], 0.f);
                }
                *(f32x4*)&sc[(lane & 15) * 20 + ((lane >> 4) << 2)] = v;
                asm volatile("s_waitcnt lgkmcnt(0)" ::: "memory");
                f32x4 rd = *(const f32x4*)&sc[(lane >> 2) * 20 + ((lane & 3) << 2)];
                const int oc = oc0 + g * 16 + (lane >> 2);
                const int xs = x0 + ((lane & 3) << 2);
                if (yy < H && xs < W)
                    *(f32x4*)&outF[((size_t)(bb * COUT + oc)) * HW + yy * W + xs] = rd;
                asm volatile("s_waitcnt lgkmcnt(0)" ::: "memory");
            }
        }
    } else {
        unsigned short* sb = (unsigned short*)(ldsAll + 41472 + wv * 2048);
#pragma unroll
        for (int rr = 0; rr < 4; ++rr) {
            const int yy = y0 + wv * 4 + rr;
#pragma unroll
            for (int g = 0; g < G; ++g)
#pragma unroll
                for (int r2 = 0; r2 < 4; ++r2) {
                    float v = acc[rr][g][r2] + bv[g];
                    if (RELU) v = fmaxf(v, 0.f);
                    sb[(((lane >> 4) << 2) + r2) * OCB + g * 16 + (lane & 15)] = f2bf(v);
                }
            asm volatile("s_waitcnt lgkmcnt(0)" ::: "memory");
#pragma unroll
            for (int j = 0; j < OCB / 32; ++j) {
                int idx = j * 64 + lane;
                int px = idx / (OCB / 8), c8 = idx % (OCB / 8);
                short8 rd = *(const short8*)&sb[px * OCB + c8 * 8];
                int gx = x0 + px;
                if (yy < H && gx < W)
                    *(short8*)&outB[((size_t)(bb * PD + 1 + yy) * PD + 1 + gx) * COUT
                                    + oc0 + c8 * 8] = rd;
            }
            asm volatile("s_waitcnt lgkmcnt(0)" ::: "memory");
        }
    }
}

// ---------------------------------------------------------------------------
// conv2 64->4 + tanh*5 -> flow.  Spill-free direct-read version (r5).
__global__ __launch_bounds__(256) void conv_flow_lite(
    const unsigned short* __restrict__ hbuf, const float* __restrict__ fw2,
    const float* __restrict__ fb2, float* __restrict__ flow, int B) {
    __shared__ float s_w[2304];              // [ch][tap][oc] = 64*9*4
    for (int u = threadIdx.x; u < 2304; u += 256) {
        int o = u & 3, tap = (u >> 2) % 9, ch = u / 36;
        s_w[u] = fw2[(size_t)(o * 64 + ch) * 9 + tap];
    }
    __syncthreads();
    const int t = threadIdx.x;
    const int py = t >> 4, px = t & 15;
    const int b = blockIdx.z;
    const int y0 = blockIdx.y * 16, x0 = blockIdx.x * 16;   // padded coords
    const unsigned short* base = hbuf + ((size_t)(b * PD + y0) * PD + x0) * 64;
    float acc[4] = {fb2[0], fb2[1], fb2[2], fb2[3]};
#pragma unroll 1
    for (int c8 = 0; c8 < 8; ++c8) {
#pragma unroll
        for (int ky = 0; ky < 3; ++ky)
#pragma unroll
            for (int kx = 0; kx < 3; ++kx) {
                short8 a8 = *(const short8*)&base[((size_t)(py + ky) * PD
                                                  + px + kx) * 64 + c8 * 8];
                const float* wp = &s_w[(c8 * 8 * 9 + ky * 3 + kx) * 4];
#pragma unroll
                for (int e = 0; e < 8; ++e) {
                    float a = bf2f((unsigned short)a8[e]);
                    float4 w4 = *(const float4*)(wp + e * 36);
                    acc[0] = fmaf(a, w4.x, acc[0]);
                    acc[1] = fmaf(a, w4.y, acc[1]);
                    acc[2] = fmaf(a, w4.z, acc[2]);
                    acc[3] = fmaf(a, w4.w, acc[3]);
                }
            }
    }
    int h = y0 + py, w = x0 + px;
    if (h < H && w < W) {
#pragma unroll
        for (int o = 0; o < 4; ++o)
            flow[(size_t)(b * 4 + o) * HW + h * W + w] = tanhf(acc[o]) * 5.0f;
    }
}

// ---------------------------------------------------------------------------
// grid sample from cat (bf16 NHWC): chunk-major threads, coalesced in+out.
__global__ __launch_bounds__(256) void grid_sample_cat(
    const unsigned short* __restrict__ cat, const float* __restrict__ flow,
    unsigned short* __restrict__ f2, int B, int total) {
    int id = blockIdx.x * 256 + threadIdx.x;
    if (id >= total) return;                 // total = B*HW*32
    int q = id & 31; int pix = id >> 5;
    int w = pix % W; int r = pix / W;
    int h = r % H;  int b = r / H;
    const bool is_img = q < 16;
    const int j = is_img ? q : q - 16;
    const int fo = is_img ? 2 : 0;
    size_t fbase = (size_t)b * 4 * HW + h * W + w;
    float sx = (float)w + flow[fbase + (size_t)fo * HW];
    float sy = (float)h + flow[fbase + (size_t)(fo + 1) * HW];
    sx = fminf(fmaxf(sx, 0.f), (float)(W - 1));
    sy = fminf(fmaxf(sy, 0.f), (float)(H - 1));
    float x0f = floorf(sx), y0f = floorf(sy);
    float x1f = fminf(x0f + 1.f, (float)(W - 1));
    float y1f = fminf(y0f + 1.f, (float)(H - 1));
    float wx = sx - x0f, wy = sy - y0f;
    int x0 = (int)x0f, x1 = (int)x1f, y0 = (int)y0f, y1 = (int)y1f;
    float w00 = (1.f - wx) * (1.f - wy), w01 = wx * (1.f - wy);
    float w10 = (1.f - wx) * wy,         w11 = wx * wy;
    const unsigned short* cb0 = cat + (size_t)b * PD2 * 320
                                + (is_img ? 128 : 0) + j * 8;
    const short8 v00 = *(const short8*)&cb0[((size_t)(1 + y0) * PD + 1 + x0) * 320];
    const short8 v01 = *(const short8*)&cb0[((size_t)(1 + y0) * PD + 1 + x1) * 320];
    const short8 v10 = *(const short8*)&cb0[((size_t)(1 + y1) * PD + 1 + x0) * 320];
    const short8 v11 = *(const short8*)&cb0[((size_t)(1 + y1) * PD + 1 + x1) * 320];
    short8 pack;
#pragma unroll
    for (int e = 0; e < 8; ++e) {
        float v = bf2f((unsigned short)v00[e]) * w00 +
                  bf2f((unsigned short)v01[e]) * w01 +
                  bf2f((unsigned short)v10[e]) * w10 +
                  bf2f((unsigned short)v11[e]) * w11;
        pack[e] = (short)f2bf(v);
    }
    *(short8*)&f2[((size_t)(b * PD + 1 + h) * PD + 1 + w) * 256 +
                  (is_img ? 0 : 128) + j * 8] = pack;
}

// ---------------------------------------------------------------------------
extern "C" void kernel_launch(void* const* d_in, const int* in_sizes, int n_in,
                              void* d_out, int out_size, void* d_ws, size_t ws_size,
                              hipStream_t stream) {
    const float* pts  = (const float*)d_in[0];
    const float* img  = (const float*)d_in[1];
    const float* hm_p = (const float*)d_in[2];
    const float* hm_i = (const float*)d_in[3];
    const float* fw1  = (const float*)d_in[4];
    const float* fb1  = (const float*)d_in[5];
    const float* fw2  = (const float*)d_in[6];
    const float* fb2  = (const float*)d_in[7];
    const float* gw1  = (const float*)d_in[8];
    const float* gb1  = (const float*)d_in[9];
    const float* gw2  = (const float*)d_in[10];
    const float* gb2  = (const float*)d_in[11];
    char* ws = (char*)d_ws;
    const int B = in_sizes[0] / (128 * HW);   // 4

    unsigned short* cat  = (unsigned short*)(ws + OFF_CAT);
    unsigned short* f2   = (unsigned short*)(ws + OFF_F2);
    unsigned short* hbuf = (unsigned short*)(ws + OFF_HBUF);
    unsigned short* go   = (unsigned short*)(ws + OFF_GO);
    float* hpn   = (float*)(ws + OFF_HPN);
    float* hin   = (float*)(ws + OFF_HIN);
    float* flow  = (float*)(ws + OFF_FLOW);
    unsigned short* wf1  = (unsigned short*)(ws + OFF_WF1);
    unsigned short* wfg1 = (unsigned short*)(ws + OFF_WFG1);
    unsigned short* wfg2 = (unsigned short*)(ws + OFF_WFG2);

    // 1. weight frag transforms
    wfrag_kernel<1><<<180, 256, 0, stream>>>(fw1, wf1, 306, 4, 720);
    wfrag_kernel<0><<<288, 256, 0, stream>>>(gw1, wfg1, 256, 8, 1152);
    wfrag_kernel<0><<<144, 256, 0, stream>>>(gw2, wfg2, 128, 8, 576);
    // 2. cat halo zero + interior build
    {
        int tot = B * 5236 * 40;
        border_zero<<<(tot + 255) / 256, 256, 0, stream>>>(cat, 40, tot);
    }
    build_cat<<<B * 180, 192, 0, stream>>>(pts, img, cat);
    // 3. heatmaps + cost volumes (NHWC records)
    {
        dim3 grid(12, 12, 2 * B);
        prep_heatmaps<<<grid, 256, 0, stream>>>(hm_p, hm_i, hpn, hin, B);
    }
    int totc = B * HW;
    cost_volume_cat<<<(totc + 255) / 256, 256, 0, stream>>>(hpn, hin, cat, B, totc);
    // 4. hbuf halo zero (aliases hpn/hin, now dead) then conv1 -> bf16 NHWC
    {
        int tot = B * 5236 * 8;
        border_zero<<<(tot + 255) / 256, 256, 0, stream>>>(hbuf, 8, tot);
        dim3 grid(12, 12, 2 * B);
        conv_mfma<10, 64, 1, true, 32><<<grid, 256, 0, stream>>>(
            cat, wf1, fb1, nullptr, hbuf, B);
    }
    // 5. conv2 64->4 + tanh*5 -> flow (spill-free lite kernel)
    {
        dim3 grid(12, 12, B);
        conv_flow_lite<<<grid, 256, 0, stream>>>(hbuf, fw2, fb2, flow, B);
    }
    // 6. halo zeros for f2/go
    {
        int tot = B * 5236 * 32;
        border_zero<<<(tot + 255) / 256, 256, 0, stream>>>(f2, 32, tot);
        int tot2 = B * 5236 * 16;
        border_zero<<<(tot2 + 255) / 256, 256, 0, stream>>>(go, 16, tot2);
    }
    // 7. grid sample (reads cat bf16) -> f2 interior
    int totg = B * HW * 32;
    grid_sample_cat<<<(totg + 255) / 256, 256, 0, stream>>>(cat, flow, f2, B, totg);
    // 8. g1 256->128 + relu -> go (padded NHWC bf16)
    {
        dim3 grid(12, 12, 2 * B);
        conv_mfma<8, 128, 1, true, 64><<<grid, 256, 0, stream>>>(
            f2, wfg1, gb1, nullptr, go, B);
    }
    // 9. g2 128->128 -> d_out (fp32 NCHW)
    {
        dim3 grid(12, 12, 2 * B);
        conv_mfma<4, 128, 0, false, 64><<<grid, 256, 0, stream>>>(
            go, wfg2, gb2, (float*)d_out, nullptr, B);
    }
}